// Round 1
// baseline (999.371 us; speedup 1.0000x reference)
//
#include <hip/hip_runtime.h>
#include <hip/hip_bf16.h>

#define NN 100000
#define NE 600000

__device__ __forceinline__ float dot4(float4 a, float4 b){
  return a.x*b.x + a.y*b.y + a.z*b.z + a.w*b.w;
}
__device__ __forceinline__ void fma4(float4& a, float s, float4 w){
  a.x += s*w.x; a.y += s*w.y; a.z += s*w.z; a.w += s*w.w;
}

// ---------------- CSR build (dst-grouped) ----------------
__global__ void count_edges(const int* __restrict__ dst, int* __restrict__ cnt){
  int e = blockIdx.x*256 + threadIdx.x;
  if (e < NE){
    unsigned d = (unsigned)dst[e];
    if (d < NN) atomicAdd(&cnt[d], 1);
  }
}

// block scans 2048 counts -> exclusive offsets (block-local) + block sum
__global__ void scan1(const int* __restrict__ cnt, int* __restrict__ offs, int* __restrict__ bsum){
  __shared__ int sh[256];
  const int tid = threadIdx.x;
  const int base = blockIdx.x*2048 + tid*8;
  int pre[8]; int s = 0;
  #pragma unroll
  for (int j=0;j<8;j++){
    int idx = base + j;
    int v = (idx < NN) ? cnt[idx] : 0;
    pre[j] = s; s += v;
  }
  sh[tid] = s;
  __syncthreads();
  for (int d=1; d<256; d<<=1){
    int t = (tid >= d) ? sh[tid-d] : 0;
    __syncthreads();
    sh[tid] += t;
    __syncthreads();
  }
  int off = (tid > 0) ? sh[tid-1] : 0;
  #pragma unroll
  for (int j=0;j<8;j++){
    int idx = base + j;
    if (idx < NN) offs[idx] = off + pre[j];
  }
  if (tid == 255) bsum[blockIdx.x] = sh[255];
}

__global__ void scan2(int* __restrict__ bsum){
  if (threadIdx.x == 0){
    int s = 0;
    for (int i=0;i<49;i++){ int t = bsum[i]; bsum[i] = s; s += t; }
  }
}

__global__ void scan3(int* __restrict__ offs, const int* __restrict__ bsum, int* __restrict__ cursor){
  int i = blockIdx.x*256 + threadIdx.x;
  if (i < NN){
    int v = offs[i] + bsum[i>>11];
    offs[i] = v; cursor[i] = v;
  }
  if (i == 0) offs[NN] = NE;
}

__global__ void fill_csr(const int* __restrict__ src, const int* __restrict__ dst,
                         int* __restrict__ cursor, int* __restrict__ csrsrc){
  int e = blockIdx.x*256 + threadIdx.x;
  if (e < NE){
    unsigned d = (unsigned)dst[e];
    unsigned s = (unsigned)src[e];
    if (d < NN && s < NN){
      int p = atomicAdd(&cursor[d], 1);
      csrsrc[p] = (int)s;
    }
  }
}

// ---------------- input MLP: h = relu(LN(x@w_in+b_in)) ----------------
__global__ __launch_bounds__(256) void input_mlp(const float* __restrict__ x,
    const float* __restrict__ win, const float* __restrict__ b,
    const float* __restrict__ lnw, const float* __restrict__ lnb,
    float* __restrict__ h)
{
  __shared__ float wsh[6*128];
  __shared__ float p2[4][2];
  const int tid = threadIdx.x;
  for (int i=tid;i<768;i+=256) wsh[i] = win[i];
  __syncthreads();
  const int nl = tid>>7, c = tid&127;
  const int n = blockIdx.x*2 + nl;
  float s = b[c];
  #pragma unroll
  for (int k=0;k<6;k++) s += x[n*6+k]*wsh[k*128+c];
  float sum = s, sq = s*s;
  #pragma unroll
  for (int o=32;o>=1;o>>=1){ sum += __shfl_xor(sum,o); sq += __shfl_xor(sq,o); }
  const int wv = tid>>6;
  if ((tid&63)==0){ p2[wv][0]=sum; p2[wv][1]=sq; }
  __syncthreads();
  float ts = p2[nl*2][0]+p2[nl*2+1][0];
  float tq = p2[nl*2][1]+p2[nl*2+1][1];
  float mean = ts*(1.f/128.f);
  float var  = tq*(1.f/128.f) - mean*mean;
  float y = (s-mean)*rsqrtf(var+1e-5f)*lnw[c]+lnb[c];
  h[(size_t)n*128+c] = fmaxf(y, 0.f);
}

// ---------------- tiled fp32 GEMM: Y = act(LN?(X@W + b)), X is Nx128 ----------------
// C: output channels (128 or 64). 32 nodes/block.
template<int C, bool HAS_BIAS, bool DO_LN, bool DO_RELU, bool GAT>
__global__ __launch_bounds__(256) void gemm128(const float* __restrict__ X,
    const float* __restrict__ W, const float* __restrict__ bias,
    const float* __restrict__ lnw, const float* __restrict__ lnb,
    const float* __restrict__ asrc, const float* __restrict__ adst,
    float* __restrict__ Y, float* __restrict__ als, float* __restrict__ ald)
{
  constexpr int TPC = C/4;        // threads covering one row's channels (float4 each)
  constexpr int NG  = 256/TPC;    // row groups per pass
  constexpr int NPB = 32;         // nodes per block
  constexpr int RPT = NPB/NG;     // rows per thread (4 for C=128, 2 for C=64)
  __shared__ float Wsh[128*C];
  __shared__ float Xsh[NPB*128];
  const int tid = threadIdx.x;
  {
    const float4* W4 = (const float4*)W;
    float4* S4 = (float4*)Wsh;
    for (int i=tid; i<128*C/4; i+=256) S4[i] = W4[i];
    const float4* X4 = (const float4*)(X + (size_t)blockIdx.x*NPB*128);
    float4* XS = (float4*)Xsh;
    for (int i=tid; i<NPB*128/4; i+=256) XS[i] = X4[i];
  }
  __syncthreads();
  const int tc = tid % TPC, tg = tid / TPC;
  float4 acc[RPT];
  float4 bv = make_float4(0.f,0.f,0.f,0.f);
  if constexpr (HAS_BIAS) bv = ((const float4*)bias)[tc];
  #pragma unroll
  for (int r=0;r<RPT;r++) acc[r] = bv;
  #pragma unroll 4
  for (int k=0;k<128;k+=4){
    float4 w0 = *(const float4*)&Wsh[(k+0)*C + tc*4];
    float4 w1 = *(const float4*)&Wsh[(k+1)*C + tc*4];
    float4 w2 = *(const float4*)&Wsh[(k+2)*C + tc*4];
    float4 w3 = *(const float4*)&Wsh[(k+3)*C + tc*4];
    #pragma unroll
    for (int r=0;r<RPT;r++){
      float4 xv = *(const float4*)&Xsh[(tg + r*NG)*128 + k];
      fma4(acc[r], xv.x, w0); fma4(acc[r], xv.y, w1);
      fma4(acc[r], xv.z, w2); fma4(acc[r], xv.w, w3);
    }
  }
  const int n0 = blockIdx.x*NPB;
  if constexpr (GAT){
    float4 av = ((const float4*)asrc)[tc];
    float4 dv = ((const float4*)adst)[tc];
    #pragma unroll
    for (int r=0;r<RPT;r++){
      const int n = n0 + tg + r*NG;
      ((float4*)&Y[(size_t)n*C])[tc] = acc[r];
      float ps = dot4(acc[r], av), pd = dot4(acc[r], dv);
      ps += __shfl_xor(ps,1); ps += __shfl_xor(ps,2);
      pd += __shfl_xor(pd,1); pd += __shfl_xor(pd,2);
      if ((tc&3)==0){
        als[n*8 + (tc>>2)] = ps;
        ald[n*8 + (tc>>2)] = pd;
      }
    }
  } else {
    #pragma unroll
    for (int r=0;r<RPT;r++){
      float4 v = acc[r];
      if constexpr (DO_LN){
        float s = v.x+v.y+v.z+v.w;
        float q = dot4(v,v);
        #pragma unroll
        for (int o=1;o<TPC;o<<=1){ s += __shfl_xor(s,o); q += __shfl_xor(q,o); }
        float mean = s*(1.0f/C);
        float var  = q*(1.0f/C) - mean*mean;
        float rr = rsqrtf(var + 1e-5f);
        float4 lw = ((const float4*)lnw)[tc];
        float4 lb = ((const float4*)lnb)[tc];
        v.x = (v.x-mean)*rr*lw.x + lb.x;
        v.y = (v.y-mean)*rr*lw.y + lb.y;
        v.z = (v.z-mean)*rr*lw.z + lb.z;
        v.w = (v.w-mean)*rr*lw.w + lb.w;
      }
      if constexpr (DO_RELU){
        v.x=fmaxf(v.x,0.f); v.y=fmaxf(v.y,0.f); v.z=fmaxf(v.z,0.f); v.w=fmaxf(v.w,0.f);
      }
      const int n = n0 + tg + r*NG;
      ((float4*)&Y[(size_t)n*C])[tc] = v;
    }
  }
}

// ---------------- per-node softmax + aggregate + LN + residual ----------------
__global__ __launch_bounds__(128) void gat_aggregate(
    const float* __restrict__ xw, const float* __restrict__ als, const float* __restrict__ ald,
    const int* __restrict__ offs, const int* __restrict__ csrsrc,
    const float* __restrict__ bg, const float* __restrict__ lnw, const float* __restrict__ lnb,
    float* __restrict__ h)
{
  const int n = blockIdx.x, tid = threadIdx.x, hd = tid>>4;
  __shared__ float aldsh[8], msh[8], ssh[8], rsc[8];
  __shared__ float ev[256];
  __shared__ int srcs[32];
  __shared__ float p2[2][2];
  if (tid < 8){
    float adv = ald[n*8+tid];
    aldsh[tid] = adv;
    float v = als[n*8+tid] + adv;     // self-loop logit
    v = v > 0.f ? v : 0.2f*v;
    msh[tid] = v; ssh[tid] = 1.0f;    // p_self = exp(0) = 1
  }
  float acc = xw[(size_t)n*128 + tid]; // self-loop message, weight 1 (pre-normalization)
  const int start = offs[n], end = offs[n+1];
  __syncthreads();
  for (int cs = start; cs < end; cs += 32){
    const int cnt = min(32, end - cs);
    if (tid < cnt) srcs[tid] = csrsrc[cs + tid];
    __syncthreads();
    for (int j = tid; j < cnt*8; j += 128){
      int e = j>>3, hh = j&7;
      float v = als[srcs[e]*8 + hh] + aldsh[hh];
      ev[j] = v > 0.f ? v : 0.2f*v;
    }
    __syncthreads();
    if (tid < 8){
      float m = msh[tid], cm = -3.0e38f;
      for (int e=0;e<cnt;e++) cm = fmaxf(cm, ev[e*8+tid]);
      float nm = fmaxf(m, cm);
      rsc[tid] = __expf(m - nm);
      msh[tid] = nm;
    }
    __syncthreads();
    for (int j = tid; j < cnt*8; j += 128) ev[j] = __expf(ev[j] - msh[j&7]);
    acc *= rsc[hd];
    __syncthreads();
    if (tid < 8){
      float ss = ssh[tid]*rsc[tid];
      for (int e=0;e<cnt;e++) ss += ev[e*8+tid];
      ssh[tid] = ss;
    }
    for (int e=0;e<cnt;e++)
      acc += ev[e*8+hd] * xw[(size_t)srcs[e]*128 + tid];
    __syncthreads();
  }
  float val = acc/ssh[hd] + bg[tid];
  // LayerNorm over 128 channels (2 waves)
  float sum = val, sq = val*val;
  #pragma unroll
  for (int o=32;o>=1;o>>=1){ sum += __shfl_xor(sum,o); sq += __shfl_xor(sq,o); }
  const int wv = tid>>6;
  if ((tid&63)==0){ p2[wv][0]=sum; p2[wv][1]=sq; }
  __syncthreads();
  float ts = p2[0][0]+p2[1][0], tq = p2[0][1]+p2[1][1];
  float mean = ts*(1.f/128.f);
  float var  = tq*(1.f/128.f) - mean*mean;
  float y = (val-mean)*rsqrtf(var+1e-5f)*lnw[tid]+lnb[tid];
  h[(size_t)n*128+tid] += fmaxf(y, 0.f);
}

// ---------------- final projection: out = o2@w3 + b3 ----------------
__global__ __launch_bounds__(256) void out_proj(const float* __restrict__ o2,
    const float* __restrict__ w3, const float* __restrict__ b3, float* __restrict__ out)
{
  __shared__ float wsh[256];
  const int tid = threadIdx.x;
  wsh[tid] = w3[tid];
  __syncthreads();
  const int g = blockIdx.x*64 + (tid>>2);
  if (g >= NN) return;
  const int oc = tid&3;
  float s = b3[oc];
  const float* row = &o2[(size_t)g*64];
  #pragma unroll 8
  for (int k=0;k<64;k++) s += row[k]*wsh[k*4+oc];
  out[(size_t)g*4+oc] = s;
}

extern "C" void kernel_launch(void* const* d_in, const int* in_sizes, int n_in,
                              void* d_out, int out_size, void* d_ws, size_t ws_size,
                              hipStream_t stream)
{
  const float* x       = (const float*)d_in[0];
  const int*   ei      = (const int*)d_in[1];
  const float* w_in    = (const float*)d_in[2];
  const float* b_in    = (const float*)d_in[3];
  const float* ln_in_w = (const float*)d_in[4];
  const float* ln_in_b = (const float*)d_in[5];
  const float* Wg      = (const float*)d_in[6];
  const float* a_src   = (const float*)d_in[7];
  const float* a_dst   = (const float*)d_in[8];
  const float* bg      = (const float*)d_in[9];
  const float* lnw     = (const float*)d_in[10];
  const float* lnb     = (const float*)d_in[11];
  const float* w1      = (const float*)d_in[12];
  const float* b1      = (const float*)d_in[13];
  const float* lnow    = (const float*)d_in[14];
  const float* lnob    = (const float*)d_in[15];
  const float* w2      = (const float*)d_in[16];
  const float* b2      = (const float*)d_in[17];
  const float* w3      = (const float*)d_in[18];
  const float* b3      = (const float*)d_in[19];
  float* out = (float*)d_out;

  char* p = (char*)d_ws;
  auto carve = [&](size_t bytes)->void*{
    void* r = (void*)p; p += (bytes + 255) & ~(size_t)255; return r;
  };
  float* h    = (float*)carve((size_t)NN*128*4);
  float* xw   = (float*)carve((size_t)NN*128*4);
  float* als  = (float*)carve((size_t)NN*8*4);
  float* ald  = (float*)carve((size_t)NN*8*4);
  int* offs   = (int*)carve((size_t)(NN+1)*4);
  int* cursor = (int*)carve((size_t)NN*4);
  int* cnt    = (int*)carve((size_t)NN*4);
  int* csrsrc = (int*)carve((size_t)NE*4);
  int* bsum   = (int*)carve(64*4);
  float* o2   = h;   // h is dead after the o1 GEMM; reuse for o2

  const int* esrc = ei;
  const int* edst = ei + NE;

  // CSR build (dst-grouped incoming-edge lists)
  hipMemsetAsync(cnt, 0, (size_t)NN*4, stream);
  count_edges<<<(NE+255)/256, 256, 0, stream>>>(edst, cnt);
  scan1<<<49, 256, 0, stream>>>(cnt, offs, bsum);
  scan2<<<1, 64, 0, stream>>>(bsum);
  scan3<<<(NN+255)/256, 256, 0, stream>>>(offs, bsum, cursor);
  fill_csr<<<(NE+255)/256, 256, 0, stream>>>(esrc, edst, cursor, csrsrc);

  // input MLP
  input_mlp<<<NN/2, 256, 0, stream>>>(x, w_in, b_in, ln_in_w, ln_in_b, h);

  // 4 GAT layers
  for (int i=0;i<4;i++){
    gemm128<128,false,false,false,true><<<NN/32, 256, 0, stream>>>(
        h, Wg + (size_t)i*128*128, nullptr, nullptr, nullptr,
        a_src + i*128, a_dst + i*128, xw, als, ald);
    gat_aggregate<<<NN, 128, 0, stream>>>(xw, als, ald, offs, csrsrc,
        bg + i*128, lnw + i*128, lnb + i*128, h);
  }

  // output MLP
  gemm128<128,true,true,true,false><<<NN/32, 256, 0, stream>>>(
      h, w1, b1, lnow, lnob, nullptr, nullptr, xw, nullptr, nullptr);
  gemm128<64,true,false,true,false><<<NN/32, 256, 0, stream>>>(
      xw, w2, b2, nullptr, nullptr, nullptr, nullptr, o2, nullptr, nullptr);
  out_proj<<<(NN+63)/64, 256, 0, stream>>>(o2, w3, b3, out);
}